// Round 10
// baseline (389.729 us; speedup 1.0000x reference)
//
#include <hip/hip_runtime.h>
#include <float.h>
#include <math.h>

// Problem constants (from reference setup_inputs)
#define LQ   512
#define LL   4096      // key length
#define DD   64        // d_qk == d_v
#define KEEP 32        // MAX_SET_SIZE
#define NB   8         // batches
#define NROWS (NB * LQ)    // 4096 flat query rows

// K1 tiling
#define RT    32           // query rows per block
#define NLC   8            // l-chunks per row (512 each)
#define LC    (LL / NLC)   // 512
#define LSP   128          // l's per staging round
#define NPAIR (LC / LSP)   // 4
#define NCAND (NLC * KEEP) // 256 candidates per row

// ---- ws layout (float units) ------------------------------------------------
// ckey : [NROWS][NCAND] uint32   4 MB   per-chunk top-32 order-keys
// cidx : [NROWS][NCAND] uint32   4 MB   their global l indices
// bm   : [NROWS][128]   uint32   2 MB   mask bitmask (bit l of row)
// VT   : [NB][DD][LL]   bf16     4 MB   v transposed for MFMA mean
#define WS_CKEY  0
#define WS_CIDX  (NROWS * NCAND)
#define WS_BM    (2 * NROWS * NCAND)
#define WS_VT    (WS_BM + NROWS * 128)
#define WS_TOTAL (WS_VT + (NB * DD * LL) / 2)   // 3,670,016 floats = 14.7 MB

#define MASKED_KEY 0x00800000u              // order-key of -FLT_MAX

typedef short  bf16x8 __attribute__((ext_vector_type(8)));
typedef float  f32x4  __attribute__((ext_vector_type(4)));

__device__ __forceinline__ float dot4(float4 a, float4 b) {
    return a.x * b.x + a.y * b.y + a.z * b.z + a.w * b.w;
}
__device__ __forceinline__ unsigned short f2bf(float f) {
    unsigned int u = __float_as_uint(f);
    return (unsigned short)((u + 0x7FFFu + ((u >> 16) & 1u)) >> 16);   // RNE
}
__device__ __forceinline__ unsigned int f2key(float f) {
    unsigned int u = __float_as_uint(f);
    return ((int)u < 0) ? ~u : (u | 0x80000000u);
}

// ============================================================================
// P0: v[b][l][d] fp32 -> VT[b][d][l] bf16 (LDS tile transpose).
// ============================================================================
#define TP_LB 256
__global__ __launch_bounds__(256) void k_vt(
    const float* __restrict__ v, unsigned short* __restrict__ vt)
{
    __shared__ unsigned short tile[DD][TP_LB + 8];   // +8: bank de-phase
    const int t  = threadIdx.x;
    const int b  = blockIdx.x >> 4;                  // 16 blocks per batch
    const int l0 = (blockIdx.x & 15) * TP_LB;

    const float4* vg = reinterpret_cast<const float4*>(v + ((size_t)b * LL + l0) * DD);
    #pragma unroll
    for (int i = 0; i < 16; ++i) {
        int j = t + 256 * i;                         // f4 idx: l = j>>4, dq = (j&15)*4
        float4 f = vg[j];
        int l = j >> 4, dq = (j & 15) * 4;
        tile[dq + 0][l] = f2bf(f.x);
        tile[dq + 1][l] = f2bf(f.y);
        tile[dq + 2][l] = f2bf(f.z);
        tile[dq + 3][l] = f2bf(f.w);
    }
    __syncthreads();
    const int d = t >> 2, seg = t & 3;               // 64 ushorts per thread
    const uint4* src = reinterpret_cast<const uint4*>(&tile[d][seg * 64]);
    uint4* dst = reinterpret_cast<uint4*>(vt + ((size_t)b * DD + d) * LL + l0 + seg * 64);
    #pragma unroll
    for (int i = 0; i < 8; ++i) dst[i] = src[i];
}

// ============================================================================
// K1: masked scores + per-chunk exact top-32 -> candidate arrays (8 MB
// instead of the 64 MB score dump), + mask ballot bitmask (2 MB) for k_mean.
// Wave owns 8 rows; lane retains 8 order-keys/row (64 VGPRs, the k_select-
// proven pattern). Per-row radix select reuses K-staging LDS as histogram.
// Global top-32 is a subset of the union of per-chunk top-32s (exact, incl.
// masked-tie quota semantics: ties at T==MASKED_KEY are dropped, weight 0).
// ============================================================================
__global__ __launch_bounds__(256)
__attribute__((amdgpu_waves_per_eu(2, 3)))
void k_scores(
    const float* __restrict__ q,
    const float* __restrict__ kmat,
    const int*   __restrict__ mask,
    unsigned int* __restrict__ ckey,
    unsigned int* __restrict__ cidx,
    uint4*        __restrict__ bm)        // [NROWS][32] uint4-units (=128 u32/row)
{
    __shared__ float4 Ss4[16 * LSP];      // 32 KB K^T [dc][l]; reused as hist after

    const int t    = threadIdx.x;
    const int wave = t >> 6;
    const int lane = t & 63;
    const int rt   = blockIdx.x >> 3;
    const int lc   = blockIdx.x & (NLC - 1);         // XCD = blockIdx%8
    const int n0   = rt * RT;
    const int b    = n0 / LQ;
    const int lbase = lc * LC;

    int qbase[8];
    #pragma unroll
    for (int p = 0; p < 8; ++p)
        qbase[p] = __builtin_amdgcn_readfirstlane((n0 + wave * 8 + p) * DD);

    const float4* kg = reinterpret_cast<const float4*>(kmat) + (size_t)b * LL * 16;

    unsigned int keys[8][8];              // [p][e], e = s*2 + half; 64 VGPRs

    for (int s = 0; s < NPAIR; ++s) {
        const int l0 = lbase + s * LSP;
        __syncthreads();
        #pragma unroll
        for (int i = 0; i < 2; ++i)
            #pragma unroll
            for (int j = 0; j < 4; ++j)
                Ss4[(wave * 4 + j) * LSP + lane + 64 * i] =
                    kg[(size_t)(l0 + lane + 64 * i) * 16 + wave * 4 + j];
        __syncthreads();

        float acc0[8], acc1[8];
        #pragma unroll
        for (int p = 0; p < 8; ++p) { acc0[p] = 0.f; acc1[p] = 0.f; }
        #pragma unroll
        for (int dc = 0; dc < 16; ++dc) {
            float4 ka = Ss4[dc * LSP + lane];
            float4 kb = Ss4[dc * LSP + 64 + lane];
            #pragma unroll
            for (int p = 0; p < 8; ++p) {
                float4 q4 = *reinterpret_cast<const float4*>(q + qbase[p] + dc * 4);
                acc0[p] += dot4(ka, q4);
                acc1[p] += dot4(kb, q4);
            }
        }
        #pragma unroll
        for (int p = 0; p < 8; ++p) {
            const int r = wave * 8 + p;
            int m0 = mask[(size_t)(n0 + r) * LL + l0 + lane];
            int m1 = mask[(size_t)(n0 + r) * LL + l0 + 64 + lane];
            unsigned long long b0 = __ballot(m0 != 0);
            unsigned long long b1 = __ballot(m1 != 0);
            if (lane == 0)
                bm[(size_t)(n0 + r) * 32 + lc * 4 + s] =
                    make_uint4((unsigned)b0, (unsigned)(b0 >> 32),
                               (unsigned)b1, (unsigned)(b1 >> 32));
            keys[p][s * 2]     = m0 ? f2key(acc0[p] * 0.125f) : MASKED_KEY;
            keys[p][s * 2 + 1] = m1 ? f2key(acc1[p] * 0.125f) : MASKED_KEY;
        }
    }
    __syncthreads();                      // all waves done reading K from Ss4

    unsigned int* hist = reinterpret_cast<unsigned int*>(Ss4) + wave * 256;

    #pragma unroll 1
    for (int p = 0; p < 8; ++p) {
        const int row = n0 + wave * 8 + p;
        unsigned int prefix = 0, quota = KEEP;
        #pragma unroll 1
        for (int pass = 0; pass < 4; ++pass) {
            const int shift = 24 - 8 * pass;
            const unsigned int hs = (pass == 0) ? 0u : (unsigned int)(32 - 8 * pass);
            reinterpret_cast<uint4*>(hist)[lane] = make_uint4(0u, 0u, 0u, 0u);
            __asm__ volatile("s_waitcnt lgkmcnt(0)" ::: "memory");
            #pragma unroll
            for (int e = 0; e < 8; ++e) {
                unsigned int k = keys[p][e];
                bool act = (pass == 0) || ((k >> hs) == prefix);
                if (act) atomicAdd(&hist[(k >> shift) & 255u], 1u);
            }
            __asm__ volatile("s_waitcnt lgkmcnt(0)" ::: "memory");
            uint4 h = reinterpret_cast<const uint4*>(hist)[lane];
            unsigned int s4  = h.x + h.y + h.z + h.w;
            unsigned int suf = s4;
            #pragma unroll
            for (int off = 1; off < 64; off <<= 1) {
                unsigned int v = (unsigned int)__shfl_down((int)suf, off);
                if (lane + off < 64) suf += v;
            }
            unsigned int above = suf - s4;
            bool cond = (suf >= quota) && (above < quota);
            unsigned int Bq = 0, nq = 0;
            if (cond) {
                unsigned int hb[4] = { h.x, h.y, h.z, h.w };
                unsigned int run = above;
                int Bj = 0;
                #pragma unroll
                for (int j = 3; j >= 0; --j) {
                    unsigned int nb = run + hb[j];
                    if (nb >= quota) { Bj = j; break; }
                    run = nb;
                }
                Bq = (unsigned int)(lane * 4 + Bj);
                nq = quota - run;
            }
            unsigned long long bal = __ballot(cond);
            int src = __ffsll(bal) - 1;
            Bq = (unsigned int)__shfl((int)Bq, src);
            nq = (unsigned int)__shfl((int)nq, src);
            prefix = (prefix << 8) | Bq;
            quota  = nq;
        }
        const unsigned int T = prefix;
        const bool take_eq = (T != MASKED_KEY);
        const unsigned long long ltm = (1ull << lane) - 1ull;
        unsigned int* ck = ckey + (size_t)row * NCAND + lc * KEEP;
        unsigned int* ci = cidx + (size_t)row * NCAND + lc * KEEP;
        int base = 0, eqbase = 0;
        #pragma unroll
        for (int e = 0; e < 8; ++e) {
            unsigned int k = keys[p][e];
            bool gt = k > T;
            bool eq = take_eq && (k == T);
            unsigned long long bgt = __ballot(gt);
            unsigned long long beq = __ballot(eq);
            int slot = -1;
            if (gt) slot = base + (int)__popcll(bgt & ltm);
            if (eq) {
                int t2 = eqbase + (int)__popcll(beq & ltm);
                if (t2 < (int)quota) slot = (KEEP - (int)quota) + t2;
            }
            base   += (int)__popcll(bgt);
            eqbase += (int)__popcll(beq);
            if (slot >= 0) {
                ck[slot] = k;
                ci[slot] = (unsigned)(lbase + (e >> 1) * 128 + (e & 1) * 64 + lane);
            }
        }
        int eqt = eqbase < (int)quota ? eqbase : (int)quota;
        int S = base + (take_eq ? eqt : 0);
        if (lane >= S && lane < KEEP) { ck[lane] = MASKED_KEY; ci[lane] = 0u; }
    }
}

// ============================================================================
// P1: masked mean via bf16 MFMA; mask from the 2 MB ballot bitmask (not the
// 64 MB int array). Writes out = sum/clip(cnt,1); k_merge adds context after.
// ============================================================================
__global__ __launch_bounds__(256) void k_mean(
    const unsigned int* __restrict__ bm,   // [NROWS][128] u32, bit l of row
    const unsigned short* __restrict__ vt,
    float* __restrict__ out)
{
    __shared__ float sums[4][4][16][16];
    __shared__ float cnt_s[4][16];

    const int t     = threadIdx.x;
    const int wave  = t >> 6;
    const int lane  = t & 63;
    const int n0    = blockIdx.x * 16;
    const int b     = n0 / LQ;
    const int row_a = lane & 15;
    const int chunk = lane >> 4;

    const unsigned int* bmrow = bm + (size_t)(n0 + row_a) * 128 + wave * 32;
    const unsigned short* vbase = vt + (size_t)b * DD * LL + wave * 1024 + chunk * 8;

    f32x4 acc[4];
    #pragma unroll
    for (int dt = 0; dt < 4; ++dt) acc[dt] = (f32x4){0.f, 0.f, 0.f, 0.f};
    int cnt = 0;

    for (int l0 = 0; l0 < 1024; l0 += 32) {
        unsigned int w = bmrow[l0 >> 5];
        unsigned int byte = (w >> (chunk * 8)) & 0xFFu;
        cnt += __popc(byte);
        unsigned int p[4];
        p[0] = ((byte &   1u) ? 0x3F80u : 0u) | ((byte &   2u) ? 0x3F800000u : 0u);
        p[1] = ((byte &   4u) ? 0x3F80u : 0u) | ((byte &   8u) ? 0x3F800000u : 0u);
        p[2] = ((byte &  16u) ? 0x3F80u : 0u) | ((byte &  32u) ? 0x3F800000u : 0u);
        p[3] = ((byte &  64u) ? 0x3F80u : 0u) | ((byte & 128u) ? 0x3F800000u : 0u);
        bf16x8 afrag = *reinterpret_cast<bf16x8*>(p);
        #pragma unroll
        for (int dt = 0; dt < 4; ++dt) {
            bf16x8 bfrag = *reinterpret_cast<const bf16x8*>(
                vbase + (size_t)(dt * 16 + row_a) * LL + l0);
            acc[dt] = __builtin_amdgcn_mfma_f32_16x16x32_bf16(afrag, bfrag, acc[dt], 0, 0, 0);
        }
    }
    cnt += __shfl_xor(cnt, 16);
    cnt += __shfl_xor(cnt, 32);
    if (lane < 16) cnt_s[wave][lane] = (float)cnt;
    #pragma unroll
    for (int dt = 0; dt < 4; ++dt)
        #pragma unroll
        for (int r = 0; r < 4; ++r)
            sums[wave][dt][chunk * 4 + r][row_a] = acc[dt][r];
    __syncthreads();

    const int d = t & 63, rgrp = t >> 6;
    #pragma unroll
    for (int rr = 0; rr < 4; ++rr) {
        const int row = rgrp * 4 + rr;
        float s = sums[0][d >> 4][row][d & 15] + sums[1][d >> 4][row][d & 15]
                + sums[2][d >> 4][row][d & 15] + sums[3][d >> 4][row][d & 15];
        float c = cnt_s[0][row] + cnt_s[1][row] + cnt_s[2][row] + cnt_s[3][row];
        if (c < 1.f) c = 1.f;
        out[(size_t)(n0 + row) * DD + d] = s / c;
    }
}

// ============================================================================
// K2 (merge): exact global top-32 from 256 candidates/row (4/lane), softmax,
// padded gather, add onto mean in out. Per-wave, zero __syncthreads.
// ============================================================================
__global__ __launch_bounds__(256, 3) void k_merge(
    const float* __restrict__ vmat,
    const unsigned int* __restrict__ ckey,
    const unsigned int* __restrict__ cidx,
    float*       __restrict__ out)
{
    __shared__ unsigned int hist[4][256];
    __shared__ unsigned int selK[4][KEEP];
    __shared__ unsigned int selI[4][KEEP];
    __shared__ float        wsel[4][KEEP];

    const int t    = threadIdx.x;
    const int wave = t >> 6;
    const int lane = t & 63;
    const int row  = blockIdx.x * 4 + wave;
    const int b    = row / LQ;

    float o = out[(size_t)row * DD + lane];          // mean (from k_mean)

    uint4 k4 = reinterpret_cast<const uint4*>(ckey + (size_t)row * NCAND)[lane];
    uint4 i4 = reinterpret_cast<const uint4*>(cidx + (size_t)row * NCAND)[lane];
    unsigned int key[4] = { k4.x, k4.y, k4.z, k4.w };
    unsigned int idx[4] = { i4.x, i4.y, i4.z, i4.w };

    unsigned int prefix = 0, quota = KEEP;
    #pragma unroll 1
    for (int pass = 0; pass < 4; ++pass) {
        const int shift = 24 - 8 * pass;
        const unsigned int hs = (pass == 0) ? 0u : (unsigned int)(32 - 8 * pass);
        reinterpret_cast<uint4*>(hist[wave])[lane] = make_uint4(0u, 0u, 0u, 0u);
        __asm__ volatile("s_waitcnt lgkmcnt(0)" ::: "memory");
        #pragma unroll
        for (int e = 0; e < 4; ++e) {
            unsigned int k = key[e];
            bool act = (pass == 0) || ((k >> hs) == prefix);
            if (act) atomicAdd(&hist[wave][(k >> shift) & 255u], 1u);
        }
        __asm__ volatile("s_waitcnt lgkmcnt(0)" ::: "memory");
        uint4 h = reinterpret_cast<const uint4*>(hist[wave])[lane];
        unsigned int s4  = h.x + h.y + h.z + h.w;
        unsigned int suf = s4;
        #pragma unroll
        for (int off = 1; off < 64; off <<= 1) {
            unsigned int v = (unsigned int)__shfl_down((int)suf, off);
            if (lane + off < 64) suf += v;
        }
        unsigned int above = suf - s4;
        bool cond = (suf >= quota) && (above < quota);
        unsigned int Bq = 0, nq = 0;
        if (cond) {
            unsigned int hb[4] = { h.x, h.y, h.z, h.w };
            unsigned int run = above;
            int Bj = 0;
            #pragma unroll
            for (int j = 3; j >= 0; --j) {
                unsigned int nb = run + hb[j];
                if (nb >= quota) { Bj = j; break; }
                run = nb;
            }
            Bq = (unsigned int)(lane * 4 + Bj);
            nq = quota - run;
        }
        unsigned long long bal = __ballot(cond);
        int src = __ffsll(bal) - 1;
        Bq = (unsigned int)__shfl((int)Bq, src);
        nq = (unsigned int)__shfl((int)nq, src);
        prefix = (prefix << 8) | Bq;
        quota  = nq;
    }
    const unsigned int T = prefix;
    const bool take_eq = (T != MASKED_KEY);
    const unsigned long long ltm = (1ull << lane) - 1ull;

    if (lane < KEEP) { wsel[wave][lane] = 0.f; selI[wave][lane] = 0u; }
    int base = 0, eqbase = 0;
    #pragma unroll
    for (int e = 0; e < 4; ++e) {
        unsigned int k = key[e];
        bool gt = k > T;
        bool eq = take_eq && (k == T);
        unsigned long long bgt = __ballot(gt);
        unsigned long long beq = __ballot(eq);
        int slot = -1;
        if (gt) slot = base + (int)__popcll(bgt & ltm);
        if (eq) {
            int t2 = eqbase + (int)__popcll(beq & ltm);
            if (t2 < (int)quota) slot = (KEEP - (int)quota) + t2;
        }
        base   += (int)__popcll(bgt);
        eqbase += (int)__popcll(beq);
        if (slot >= 0) { selK[wave][slot] = k; selI[wave][slot] = idx[e]; }
    }
    int eqt = eqbase < (int)quota ? eqbase : (int)quota;
    const int S = base + (take_eq ? eqt : 0);
    __asm__ volatile("s_waitcnt lgkmcnt(0)" ::: "memory");

    if (S > 0) {
        float vj = -FLT_MAX;
        if (lane < S) {
            unsigned int kk = selK[wave][lane];
            unsigned int u = (kk & 0x80000000u) ? (kk ^ 0x80000000u) : ~kk;
            vj = __uint_as_float(u);
        }
        float mx = vj;
        #pragma unroll
        for (int off = 1; off < 64; off <<= 1) mx = fmaxf(mx, __shfl_xor(mx, off));
        float e = (lane < S) ? expf(vj - mx) : 0.f;
        float sum = e;
        #pragma unroll
        for (int off = 1; off < 64; off <<= 1) sum += __shfl_xor(sum, off);
        if (lane < S) wsel[wave][lane] = e / sum;
        __asm__ volatile("s_waitcnt lgkmcnt(0)" ::: "memory");
        const float* vb = vmat + (size_t)b * LL * DD + lane;
        #pragma unroll
        for (int j = 0; j < KEEP; ++j) {
            float wj = wsel[wave][j];
            unsigned int ij = selI[wave][j];
            o += wj * vb[(size_t)ij * DD];
        }
    }
    out[(size_t)row * DD + lane] = o;
}

// ============================================================================
// Fallback (proven round-1 monolith) in case ws_size < WS_TOTAL*4.
// ============================================================================
#define QT   2
#define NT   256
#define NTILES (LL / NT)

__global__ __launch_bounds__(NT, 4) void ga_fused_fb(
    const float* __restrict__ q, const float* __restrict__ kmat,
    const float* __restrict__ vmat, const int* __restrict__ mask,
    float* __restrict__ out)
{
    __shared__ float sc[QT][LL];
    __shared__ float q_s[QT][DD];
    __shared__ unsigned long long mbits[QT][LL / 64];
    __shared__ float redv[4][QT][DD];
    __shared__ float mean_s[QT][DD];
    __shared__ int   count_s[QT];
    __shared__ int   sel_idx[QT][KEEP];
    __shared__ float sel_val[QT][KEEP];
    __shared__ int   sel_cnt[QT];
    __shared__ float wred[4];
    __shared__ int   ired[4];
    __shared__ int   brk;
    __shared__ float wgt[QT][KEEP];

    const int t = threadIdx.x, wave = t >> 6, lane = t & 63;
    const int n0 = blockIdx.x * QT, b = n0 / LQ;

    if (t < QT) sel_cnt[t] = 0;
    if (t < QT * DD) q_s[t >> 6][t & 63] = q[(size_t)(n0 + (t >> 6)) * DD + (t & 63)];
    __syncthreads();

    const float4* q4_0 = reinterpret_cast<const float4*>(&q_s[0][0]);
    const float4* q4_1 = reinterpret_cast<const float4*>(&q_s[1][0]);
    for (int tile = 0; tile < NTILES; ++tile) {
        int l = tile * NT + t;
        const float4* kr = reinterpret_cast<const float4*>(kmat + (size_t)(b * LL + l) * DD);
        float d0 = 0.f, d1 = 0.f;
        #pragma unroll
        for (int i = 0; i < 16; ++i) {
            float4 kk = kr[i], qa = q4_0[i], qb = q4_1[i];
            d0 += kk.x * qa.x + kk.y * qa.y + kk.z * qa.z + kk.w * qa.w;
            d1 += kk.x * qb.x + kk.y * qb.y + kk.z * qb.z + kk.w * qb.w;
        }
        int mv0 = mask[(size_t)n0 * LL + l];
        int mv1 = mask[(size_t)(n0 + 1) * LL + l];
        unsigned long long b0 = __ballot(mv0 != 0);
        unsigned long long b1 = __ballot(mv1 != 0);
        if (lane == 0) { mbits[0][tile * 4 + wave] = b0; mbits[1][tile * 4 + wave] = b1; }
        sc[0][l] = mv0 ? d0 * 0.125f : -FLT_MAX;
        sc[1][l] = mv1 ? d1 * 0.125f : -FLT_MAX;
    }
    __syncthreads();

    if (wave < QT) {
        int c = (int)__popcll(mbits[wave][lane]);
        for (int off = 32; off >= 1; off >>= 1) c += __shfl_down(c, off);
        if (lane == 0) count_s[wave] = c;
    }
    {
        float acc0 = 0.f, acc1 = 0.f;
        const int g = wave, d = lane;
        for (int wi = 0; wi < LL / 64; ++wi) {
            unsigned long long w0 = mbits[0][wi], w1 = mbits[1][wi];
            const float* vp = vmat + (size_t)(b * LL + wi * 64 + g) * DD + d;
            #pragma unroll 4
            for (int ii = 0; ii < 16; ++ii) {
                int sh = g + 4 * ii;
                float vv = vp[(size_t)(4 * ii) * DD];
                if ((w0 >> sh) & 1ULL) acc0 += vv;
                if ((w1 >> sh) & 1ULL) acc1 += vv;
            }
        }
        redv[g][0][d] = acc0; redv[g][1][d] = acc1;
    }
    __syncthreads();
    if (t < QT * DD) {
        int qt = t >> 6, dd = t & 63;
        float s2 = redv[0][qt][dd] + redv[1][qt][dd] + redv[2][qt][dd] + redv[3][qt][dd];
        int c = count_s[qt]; if (c < 1) c = 1;
        mean_s[qt][dd] = s2 / (float)c;
    }
    __syncthreads();

    for (int qt = 0; qt < QT; ++qt) {
        for (int s = 0; s < KEEP; ++s) {
            float m = -FLT_MAX; int mi = LL;
            for (int j = 0; j < NTILES; ++j) {
                int l = j * NT + t;
                float val = sc[qt][l];
                if (val > m) { m = val; mi = l; }
            }
            for (int off = 32; off >= 1; off >>= 1) {
                float ov = __shfl_down(m, off);
                int   oi = __shfl_down(mi, off);
                if (ov > m || (ov == m && oi < mi)) { m = ov; mi = oi; }
            }
            if (lane == 0) { wred[wave] = m; ired[wave] = mi; }
            __syncthreads();
            if (t == 0) {
                float bv = wred[0]; int bi = ired[0];
                for (int w2 = 1; w2 < 4; ++w2) {
                    float ov = wred[w2]; int oi = ired[w2];
                    if (ov > bv || (ov == bv && oi < bi)) { bv = ov; bi = oi; }
                }
                if (bv > -FLT_MAX) {
                    sel_idx[qt][s] = bi; sel_val[qt][s] = bv; sel_cnt[qt] = s + 1;
                    sc[qt][bi] = -FLT_MAX; brk = 0;
                } else brk = 1;
            }
            __syncthreads();
            if (brk) break;
        }
    }

    if (wave < QT) {
        int qt = wave, S = sel_cnt[qt];
        if (S > 0) {
            float mx = sel_val[qt][0];
            float e = 0.f;
            if (lane < S) e = expf(sel_val[qt][lane] - mx);
            float ssum = e;
            for (int off = 32; off >= 1; off >>= 1) ssum += __shfl_xor(ssum, off);
            if (lane < S) wgt[qt][lane] = e / ssum;
        }
    }
    __syncthreads();
    if (wave < QT) {
        int qt = wave, S = sel_cnt[qt];
        float o = mean_s[qt][lane];
        for (int j = 0; j < S; ++j)
            o += wgt[qt][j] * vmat[(size_t)(b * LL + sel_idx[qt][j]) * DD + lane];
        out[(size_t)(n0 + qt) * DD + lane] = o;
    }
}

// ============================================================================
extern "C" void kernel_launch(void* const* d_in, const int* in_sizes, int n_in,
                              void* d_out, int out_size, void* d_ws, size_t ws_size,
                              hipStream_t stream) {
    const float* q    = (const float*)d_in[0];
    const float* kmat = (const float*)d_in[1];
    const float* vmat = (const float*)d_in[2];
    const int*   mask = (const int*)d_in[3];
    float* out = (float*)d_out;

    const size_t need = (size_t)WS_TOTAL * sizeof(float);   // 14.7 MB
    if (ws_size >= need) {
        float* ws = (float*)d_ws;
        unsigned int*   ckey = (unsigned int*)(ws + WS_CKEY);
        unsigned int*   cidx = (unsigned int*)(ws + WS_CIDX);
        unsigned int*   bmw  = (unsigned int*)(ws + WS_BM);
        unsigned short* vt   = (unsigned short*)(ws + WS_VT);
        hipLaunchKernelGGL(k_scores, dim3((NROWS / RT) * NLC), dim3(256), 0, stream,
                           q, kmat, mask, ckey, cidx, (uint4*)bmw);
        hipLaunchKernelGGL(k_vt, dim3(NB * 16), dim3(256), 0, stream, vmat, vt);
        hipLaunchKernelGGL(k_mean, dim3(NROWS / 16), dim3(256), 0, stream,
                           bmw, vt, out);
        hipLaunchKernelGGL(k_merge, dim3(NROWS / 4), dim3(256), 0, stream,
                           vmat, ckey, cidx, out);
    } else {
        hipLaunchKernelGGL(ga_fused_fb, dim3(NROWS / QT), dim3(NT), 0, stream,
                           q, kmat, vmat, mask, out);
    }
}

// Round 11
// 323.227 us; speedup vs baseline: 1.2057x; 1.2057x over previous
//
#include <hip/hip_runtime.h>
#include <float.h>
#include <math.h>

// Problem constants (from reference setup_inputs)
#define LQ   512
#define LL   4096      // key length
#define DD   64        // d_qk == d_v
#define KEEP 32        // MAX_SET_SIZE
#define NB   8         // batches
#define NROWS (NB * LQ)    // 4096 flat query rows

// K1 tiling
#define RT    32           // query rows per block
#define NLC   8            // l-chunks per row (512 each)
#define LC    (LL / NLC)   // 512
#define LSP   128          // l's per staging round
#define NPAIR (LC / LSP)   // 4
#define NCAND (NLC * KEEP) // 256 candidates per row

// ---- ws layout (float units) ------------------------------------------------
// ckey : [NROWS][NCAND] uint32   4 MB   per-chunk top-32 order-keys
// cidx : [NROWS][NCAND] uint32   4 MB   their global l indices
// bm   : [NROWS][128]   uint32   2 MB   mask bitmask (bit l of row)
// VT   : [NB][DD][LL]   bf16     4 MB   v transposed for MFMA mean
#define WS_CKEY  0
#define WS_CIDX  (NROWS * NCAND)
#define WS_BM    (2 * NROWS * NCAND)
#define WS_VT    (WS_BM + NROWS * 128)
#define WS_TOTAL (WS_VT + (NB * DD * LL) / 2)   // 3,670,016 floats = 14.7 MB

#define MASKED_KEY 0x00800000u              // order-key of -FLT_MAX

typedef short  bf16x8 __attribute__((ext_vector_type(8)));
typedef float  f32x4  __attribute__((ext_vector_type(4)));

__device__ __forceinline__ float dot4(float4 a, float4 b) {
    return a.x * b.x + a.y * b.y + a.z * b.z + a.w * b.w;
}
__device__ __forceinline__ unsigned short f2bf(float f) {
    unsigned int u = __float_as_uint(f);
    return (unsigned short)((u + 0x7FFFu + ((u >> 16) & 1u)) >> 16);   // RNE
}
__device__ __forceinline__ unsigned int f2key(float f) {
    unsigned int u = __float_as_uint(f);
    return ((int)u < 0) ? ~u : (u | 0x80000000u);
}

// ============================================================================
// P0: v[b][l][d] fp32 -> VT[b][d][l] bf16 (LDS tile transpose).
// ============================================================================
#define TP_LB 256
__global__ __launch_bounds__(256) void k_vt(
    const float* __restrict__ v, unsigned short* __restrict__ vt)
{
    __shared__ unsigned short tile[DD][TP_LB + 8];   // +8: bank de-phase
    const int t  = threadIdx.x;
    const int b  = blockIdx.x >> 4;                  // 16 blocks per batch
    const int l0 = (blockIdx.x & 15) * TP_LB;

    const float4* vg = reinterpret_cast<const float4*>(v + ((size_t)b * LL + l0) * DD);
    #pragma unroll
    for (int i = 0; i < 16; ++i) {
        int j = t + 256 * i;                         // f4 idx: l = j>>4, dq = (j&15)*4
        float4 f = vg[j];
        int l = j >> 4, dq = (j & 15) * 4;
        tile[dq + 0][l] = f2bf(f.x);
        tile[dq + 1][l] = f2bf(f.y);
        tile[dq + 2][l] = f2bf(f.z);
        tile[dq + 3][l] = f2bf(f.w);
    }
    __syncthreads();
    const int d = t >> 2, seg = t & 3;               // 64 ushorts per thread
    const uint4* src = reinterpret_cast<const uint4*>(&tile[d][seg * 64]);
    uint4* dst = reinterpret_cast<uint4*>(vt + ((size_t)b * DD + d) * LL + l0 + seg * 64);
    #pragma unroll
    for (int i = 0; i < 8; ++i) dst[i] = src[i];
}

// ============================================================================
// K1: masked scores + per-chunk exact top-32 -> candidate arrays, + mask
// ballot bitmask for k_mean. Wave owns 8 rows; lane retains 8 order-keys/row
// in 64 VGPRs. Selection loops are FULLY UNROLLED: any runtime index into
// keys[][] demotes it to scratch (R10: 67 MB spill traffic, dur 113->270 us).
// Histogram is 4-replica (per 16-lane group) to cut same-bucket LDS-atomic
// serialization (R10: SQ_LDS_BANK_CONFLICT 1.06e7 from concentrated digits).
// ============================================================================
__global__ __launch_bounds__(256)
__attribute__((amdgpu_waves_per_eu(2, 3)))
void k_scores(
    const float* __restrict__ q,
    const float* __restrict__ kmat,
    const int*   __restrict__ mask,
    unsigned int* __restrict__ ckey,
    unsigned int* __restrict__ cidx,
    uint4*        __restrict__ bm)        // [NROWS][32] uint4-units (=128 u32/row)
{
    __shared__ float4 Ss4[16 * LSP];      // 32 KB K^T [dc][l]; reused as hists after

    const int t    = threadIdx.x;
    const int wave = t >> 6;
    const int lane = t & 63;
    const int rt   = blockIdx.x >> 3;
    const int lc   = blockIdx.x & (NLC - 1);         // XCD = blockIdx%8
    const int n0   = rt * RT;
    const int b    = n0 / LQ;
    const int lbase = lc * LC;

    int qbase[8];
    #pragma unroll
    for (int p = 0; p < 8; ++p)
        qbase[p] = __builtin_amdgcn_readfirstlane((n0 + wave * 8 + p) * DD);

    const float4* kg = reinterpret_cast<const float4*>(kmat) + (size_t)b * LL * 16;

    unsigned int keys[8][8];              // [p][e], e = s*2 + half; 64 VGPRs

    for (int s = 0; s < NPAIR; ++s) {
        const int l0 = lbase + s * LSP;
        __syncthreads();
        #pragma unroll
        for (int i = 0; i < 2; ++i)
            #pragma unroll
            for (int j = 0; j < 4; ++j)
                Ss4[(wave * 4 + j) * LSP + lane + 64 * i] =
                    kg[(size_t)(l0 + lane + 64 * i) * 16 + wave * 4 + j];
        __syncthreads();

        float acc0[8], acc1[8];
        #pragma unroll
        for (int p = 0; p < 8; ++p) { acc0[p] = 0.f; acc1[p] = 0.f; }
        #pragma unroll
        for (int dc = 0; dc < 16; ++dc) {
            float4 ka = Ss4[dc * LSP + lane];
            float4 kb = Ss4[dc * LSP + 64 + lane];
            #pragma unroll
            for (int p = 0; p < 8; ++p) {
                float4 q4 = *reinterpret_cast<const float4*>(q + qbase[p] + dc * 4);
                acc0[p] += dot4(ka, q4);
                acc1[p] += dot4(kb, q4);
            }
        }
        #pragma unroll
        for (int p = 0; p < 8; ++p) {
            const int r = wave * 8 + p;
            int m0 = mask[(size_t)(n0 + r) * LL + l0 + lane];
            int m1 = mask[(size_t)(n0 + r) * LL + l0 + 64 + lane];
            unsigned long long b0 = __ballot(m0 != 0);
            unsigned long long b1 = __ballot(m1 != 0);
            if (lane == 0)
                bm[(size_t)(n0 + r) * 32 + lc * 4 + s] =
                    make_uint4((unsigned)b0, (unsigned)(b0 >> 32),
                               (unsigned)b1, (unsigned)(b1 >> 32));
            switch (s) {   // constant store index (keys must stay in VGPRs)
                case 0: keys[p][0] = m0 ? f2key(acc0[p] * 0.125f) : MASKED_KEY;
                        keys[p][1] = m1 ? f2key(acc1[p] * 0.125f) : MASKED_KEY; break;
                case 1: keys[p][2] = m0 ? f2key(acc0[p] * 0.125f) : MASKED_KEY;
                        keys[p][3] = m1 ? f2key(acc1[p] * 0.125f) : MASKED_KEY; break;
                case 2: keys[p][4] = m0 ? f2key(acc0[p] * 0.125f) : MASKED_KEY;
                        keys[p][5] = m1 ? f2key(acc1[p] * 0.125f) : MASKED_KEY; break;
                default:keys[p][6] = m0 ? f2key(acc0[p] * 0.125f) : MASKED_KEY;
                        keys[p][7] = m1 ? f2key(acc1[p] * 0.125f) : MASKED_KEY; break;
            }
        }
    }
    __syncthreads();                      // all waves done reading K from Ss4

    // 4-replica histogram: wave region = 1024 u32 (4 copies x 256 buckets)
    unsigned int* hist = reinterpret_cast<unsigned int*>(Ss4) + wave * 1024;
    unsigned int* myh  = hist + (lane >> 4) * 256;   // this lane's replica

    #pragma unroll
    for (int p = 0; p < 8; ++p) {
        const int row = n0 + wave * 8 + p;
        unsigned int prefix = 0, quota = KEEP;
        #pragma unroll
        for (int pass = 0; pass < 4; ++pass) {
            const int shift = 24 - 8 * pass;
            const unsigned int hs = (pass == 0) ? 0u : (unsigned int)(32 - 8 * pass);
            #pragma unroll
            for (int i = 0; i < 4; ++i)
                reinterpret_cast<uint4*>(hist)[lane + 64 * i] = make_uint4(0u, 0u, 0u, 0u);
            __asm__ volatile("s_waitcnt lgkmcnt(0)" ::: "memory");
            #pragma unroll
            for (int e = 0; e < 8; ++e) {
                unsigned int k = keys[p][e];
                bool act = (pass == 0) || ((k >> hs) == prefix);
                if (act) atomicAdd(&myh[(k >> shift) & 255u], 1u);
            }
            __asm__ volatile("s_waitcnt lgkmcnt(0)" ::: "memory");
            uint4 h0 = reinterpret_cast<const uint4*>(hist)[lane];
            uint4 h1 = reinterpret_cast<const uint4*>(hist + 256)[lane];
            uint4 h2 = reinterpret_cast<const uint4*>(hist + 512)[lane];
            uint4 h3 = reinterpret_cast<const uint4*>(hist + 768)[lane];
            uint4 h = make_uint4(h0.x + h1.x + h2.x + h3.x,
                                 h0.y + h1.y + h2.y + h3.y,
                                 h0.z + h1.z + h2.z + h3.z,
                                 h0.w + h1.w + h2.w + h3.w);
            unsigned int s4  = h.x + h.y + h.z + h.w;
            unsigned int suf = s4;
            #pragma unroll
            for (int off = 1; off < 64; off <<= 1) {
                unsigned int v = (unsigned int)__shfl_down((int)suf, off);
                if (lane + off < 64) suf += v;
            }
            unsigned int above = suf - s4;
            bool cond = (suf >= quota) && (above < quota);
            unsigned int Bq = 0, nq = 0;
            if (cond) {
                unsigned int hb[4] = { h.x, h.y, h.z, h.w };
                unsigned int run = above;
                int Bj = 0;
                #pragma unroll
                for (int j = 3; j >= 0; --j) {
                    unsigned int nb = run + hb[j];
                    if (nb >= quota) { Bj = j; break; }
                    run = nb;
                }
                Bq = (unsigned int)(lane * 4 + Bj);
                nq = quota - run;
            }
            unsigned long long bal = __ballot(cond);
            int src = __ffsll(bal) - 1;
            Bq = (unsigned int)__shfl((int)Bq, src);
            nq = (unsigned int)__shfl((int)nq, src);
            prefix = (prefix << 8) | Bq;
            quota  = nq;
        }
        const unsigned int T = prefix;
        const bool take_eq = (T != MASKED_KEY);
        const unsigned long long ltm = (1ull << lane) - 1ull;
        unsigned int* ck = ckey + (size_t)row * NCAND + lc * KEEP;
        unsigned int* ci = cidx + (size_t)row * NCAND + lc * KEEP;
        int base = 0, eqbase = 0;
        #pragma unroll
        for (int e = 0; e < 8; ++e) {
            unsigned int k = keys[p][e];
            bool gt = k > T;
            bool eq = take_eq && (k == T);
            unsigned long long bgt = __ballot(gt);
            unsigned long long beq = __ballot(eq);
            int slot = -1;
            if (gt) slot = base + (int)__popcll(bgt & ltm);
            if (eq) {
                int t2 = eqbase + (int)__popcll(beq & ltm);
                if (t2 < (int)quota) slot = (KEEP - (int)quota) + t2;
            }
            base   += (int)__popcll(bgt);
            eqbase += (int)__popcll(beq);
            if (slot >= 0) {
                ck[slot] = k;
                ci[slot] = (unsigned)(lbase + (e >> 1) * 128 + (e & 1) * 64 + lane);
            }
        }
        int eqt = eqbase < (int)quota ? eqbase : (int)quota;
        int S = base + (take_eq ? eqt : 0);
        if (lane >= S && lane < KEEP) { ck[lane] = MASKED_KEY; ci[lane] = 0u; }
    }
}

// ============================================================================
// P1: masked mean via bf16 MFMA; mask from the 2 MB ballot bitmask (not the
// 64 MB int array). Writes out = sum/clip(cnt,1); k_merge adds context after.
// ============================================================================
__global__ __launch_bounds__(256) void k_mean(
    const unsigned int* __restrict__ bm,   // [NROWS][128] u32, bit l of row
    const unsigned short* __restrict__ vt,
    float* __restrict__ out)
{
    __shared__ float sums[4][4][16][16];
    __shared__ float cnt_s[4][16];

    const int t     = threadIdx.x;
    const int wave  = t >> 6;
    const int lane  = t & 63;
    const int n0    = blockIdx.x * 16;
    const int b     = n0 / LQ;
    const int row_a = lane & 15;
    const int chunk = lane >> 4;

    const unsigned int* bmrow = bm + (size_t)(n0 + row_a) * 128 + wave * 32;
    const unsigned short* vbase = vt + (size_t)b * DD * LL + wave * 1024 + chunk * 8;

    f32x4 acc[4];
    #pragma unroll
    for (int dt = 0; dt < 4; ++dt) acc[dt] = (f32x4){0.f, 0.f, 0.f, 0.f};
    int cnt = 0;

    for (int l0 = 0; l0 < 1024; l0 += 32) {
        unsigned int w = bmrow[l0 >> 5];
        unsigned int byte = (w >> (chunk * 8)) & 0xFFu;
        cnt += __popc(byte);
        unsigned int p[4];
        p[0] = ((byte &   1u) ? 0x3F80u : 0u) | ((byte &   2u) ? 0x3F800000u : 0u);
        p[1] = ((byte &   4u) ? 0x3F80u : 0u) | ((byte &   8u) ? 0x3F800000u : 0u);
        p[2] = ((byte &  16u) ? 0x3F80u : 0u) | ((byte &  32u) ? 0x3F800000u : 0u);
        p[3] = ((byte &  64u) ? 0x3F80u : 0u) | ((byte & 128u) ? 0x3F800000u : 0u);
        bf16x8 afrag = *reinterpret_cast<bf16x8*>(p);
        #pragma unroll
        for (int dt = 0; dt < 4; ++dt) {
            bf16x8 bfrag = *reinterpret_cast<const bf16x8*>(
                vbase + (size_t)(dt * 16 + row_a) * LL + l0);
            acc[dt] = __builtin_amdgcn_mfma_f32_16x16x32_bf16(afrag, bfrag, acc[dt], 0, 0, 0);
        }
    }
    cnt += __shfl_xor(cnt, 16);
    cnt += __shfl_xor(cnt, 32);
    if (lane < 16) cnt_s[wave][lane] = (float)cnt;
    #pragma unroll
    for (int dt = 0; dt < 4; ++dt)
        #pragma unroll
        for (int r = 0; r < 4; ++r)
            sums[wave][dt][chunk * 4 + r][row_a] = acc[dt][r];
    __syncthreads();

    const int d = t & 63, rgrp = t >> 6;
    #pragma unroll
    for (int rr = 0; rr < 4; ++rr) {
        const int row = rgrp * 4 + rr;
        float s = sums[0][d >> 4][row][d & 15] + sums[1][d >> 4][row][d & 15]
                + sums[2][d >> 4][row][d & 15] + sums[3][d >> 4][row][d & 15];
        float c = cnt_s[0][row] + cnt_s[1][row] + cnt_s[2][row] + cnt_s[3][row];
        if (c < 1.f) c = 1.f;
        out[(size_t)(n0 + row) * DD + d] = s / c;
    }
}

// ============================================================================
// K2 (merge): exact global top-32 from 256 candidates/row (4/lane), softmax,
// padded gather, add onto mean in out. Per-wave, zero __syncthreads.
// ============================================================================
__global__ __launch_bounds__(256, 3) void k_merge(
    const float* __restrict__ vmat,
    const unsigned int* __restrict__ ckey,
    const unsigned int* __restrict__ cidx,
    float*       __restrict__ out)
{
    __shared__ unsigned int hist[4][256];
    __shared__ unsigned int selK[4][KEEP];
    __shared__ unsigned int selI[4][KEEP];
    __shared__ float        wsel[4][KEEP];

    const int t    = threadIdx.x;
    const int wave = t >> 6;
    const int lane = t & 63;
    const int row  = blockIdx.x * 4 + wave;
    const int b    = row / LQ;

    float o = out[(size_t)row * DD + lane];          // mean (from k_mean)

    uint4 k4 = reinterpret_cast<const uint4*>(ckey + (size_t)row * NCAND)[lane];
    uint4 i4 = reinterpret_cast<const uint4*>(cidx + (size_t)row * NCAND)[lane];
    unsigned int key[4] = { k4.x, k4.y, k4.z, k4.w };
    unsigned int idx[4] = { i4.x, i4.y, i4.z, i4.w };

    unsigned int prefix = 0, quota = KEEP;
    #pragma unroll
    for (int pass = 0; pass < 4; ++pass) {
        const int shift = 24 - 8 * pass;
        const unsigned int hs = (pass == 0) ? 0u : (unsigned int)(32 - 8 * pass);
        reinterpret_cast<uint4*>(hist[wave])[lane] = make_uint4(0u, 0u, 0u, 0u);
        __asm__ volatile("s_waitcnt lgkmcnt(0)" ::: "memory");
        #pragma unroll
        for (int e = 0; e < 4; ++e) {
            unsigned int k = key[e];
            bool act = (pass == 0) || ((k >> hs) == prefix);
            if (act) atomicAdd(&hist[wave][(k >> shift) & 255u], 1u);
        }
        __asm__ volatile("s_waitcnt lgkmcnt(0)" ::: "memory");
        uint4 h = reinterpret_cast<const uint4*>(hist[wave])[lane];
        unsigned int s4  = h.x + h.y + h.z + h.w;
        unsigned int suf = s4;
        #pragma unroll
        for (int off = 1; off < 64; off <<= 1) {
            unsigned int v = (unsigned int)__shfl_down((int)suf, off);
            if (lane + off < 64) suf += v;
        }
        unsigned int above = suf - s4;
        bool cond = (suf >= quota) && (above < quota);
        unsigned int Bq = 0, nq = 0;
        if (cond) {
            unsigned int hb[4] = { h.x, h.y, h.z, h.w };
            unsigned int run = above;
            int Bj = 0;
            #pragma unroll
            for (int j = 3; j >= 0; --j) {
                unsigned int nb = run + hb[j];
                if (nb >= quota) { Bj = j; break; }
                run = nb;
            }
            Bq = (unsigned int)(lane * 4 + Bj);
            nq = quota - run;
        }
        unsigned long long bal = __ballot(cond);
        int src = __ffsll(bal) - 1;
        Bq = (unsigned int)__shfl((int)Bq, src);
        nq = (unsigned int)__shfl((int)nq, src);
        prefix = (prefix << 8) | Bq;
        quota  = nq;
    }
    const unsigned int T = prefix;
    const bool take_eq = (T != MASKED_KEY);
    const unsigned long long ltm = (1ull << lane) - 1ull;

    if (lane < KEEP) { wsel[wave][lane] = 0.f; selI[wave][lane] = 0u; }
    int base = 0, eqbase = 0;
    #pragma unroll
    for (int e = 0; e < 4; ++e) {
        unsigned int k = key[e];
        bool gt = k > T;
        bool eq = take_eq && (k == T);
        unsigned long long bgt = __ballot(gt);
        unsigned long long beq = __ballot(eq);
        int slot = -1;
        if (gt) slot = base + (int)__popcll(bgt & ltm);
        if (eq) {
            int t2 = eqbase + (int)__popcll(beq & ltm);
            if (t2 < (int)quota) slot = (KEEP - (int)quota) + t2;
        }
        base   += (int)__popcll(bgt);
        eqbase += (int)__popcll(beq);
        if (slot >= 0) { selK[wave][slot] = k; selI[wave][slot] = idx[e]; }
    }
    int eqt = eqbase < (int)quota ? eqbase : (int)quota;
    const int S = base + (take_eq ? eqt : 0);
    __asm__ volatile("s_waitcnt lgkmcnt(0)" ::: "memory");

    if (S > 0) {
        float vj = -FLT_MAX;
        if (lane < S) {
            unsigned int kk = selK[wave][lane];
            unsigned int u = (kk & 0x80000000u) ? (kk ^ 0x80000000u) : ~kk;
            vj = __uint_as_float(u);
        }
        float mx = vj;
        #pragma unroll
        for (int off = 1; off < 64; off <<= 1) mx = fmaxf(mx, __shfl_xor(mx, off));
        float e = (lane < S) ? expf(vj - mx) : 0.f;
        float sum = e;
        #pragma unroll
        for (int off = 1; off < 64; off <<= 1) sum += __shfl_xor(sum, off);
        if (lane < S) wsel[wave][lane] = e / sum;
        __asm__ volatile("s_waitcnt lgkmcnt(0)" ::: "memory");
        const float* vb = vmat + (size_t)b * LL * DD + lane;
        #pragma unroll
        for (int j = 0; j < KEEP; ++j) {
            float wj = wsel[wave][j];
            unsigned int ij = selI[wave][j];
            o += wj * vb[(size_t)ij * DD];
        }
    }
    out[(size_t)row * DD + lane] = o;
}

// ============================================================================
// Fallback (proven round-1 monolith) in case ws_size < WS_TOTAL*4.
// ============================================================================
#define QT   2
#define NT   256
#define NTILES (LL / NT)

__global__ __launch_bounds__(NT, 4) void ga_fused_fb(
    const float* __restrict__ q, const float* __restrict__ kmat,
    const float* __restrict__ vmat, const int* __restrict__ mask,
    float* __restrict__ out)
{
    __shared__ float sc[QT][LL];
    __shared__ float q_s[QT][DD];
    __shared__ unsigned long long mbits[QT][LL / 64];
    __shared__ float redv[4][QT][DD];
    __shared__ float mean_s[QT][DD];
    __shared__ int   count_s[QT];
    __shared__ int   sel_idx[QT][KEEP];
    __shared__ float sel_val[QT][KEEP];
    __shared__ int   sel_cnt[QT];
    __shared__ float wred[4];
    __shared__ int   ired[4];
    __shared__ int   brk;
    __shared__ float wgt[QT][KEEP];

    const int t = threadIdx.x, wave = t >> 6, lane = t & 63;
    const int n0 = blockIdx.x * QT, b = n0 / LQ;

    if (t < QT) sel_cnt[t] = 0;
    if (t < QT * DD) q_s[t >> 6][t & 63] = q[(size_t)(n0 + (t >> 6)) * DD + (t & 63)];
    __syncthreads();

    const float4* q4_0 = reinterpret_cast<const float4*>(&q_s[0][0]);
    const float4* q4_1 = reinterpret_cast<const float4*>(&q_s[1][0]);
    for (int tile = 0; tile < NTILES; ++tile) {
        int l = tile * NT + t;
        const float4* kr = reinterpret_cast<const float4*>(kmat + (size_t)(b * LL + l) * DD);
        float d0 = 0.f, d1 = 0.f;
        #pragma unroll
        for (int i = 0; i < 16; ++i) {
            float4 kk = kr[i], qa = q4_0[i], qb = q4_1[i];
            d0 += kk.x * qa.x + kk.y * qa.y + kk.z * qa.z + kk.w * qa.w;
            d1 += kk.x * qb.x + kk.y * qb.y + kk.z * qb.z + kk.w * qb.w;
        }
        int mv0 = mask[(size_t)n0 * LL + l];
        int mv1 = mask[(size_t)(n0 + 1) * LL + l];
        unsigned long long b0 = __ballot(mv0 != 0);
        unsigned long long b1 = __ballot(mv1 != 0);
        if (lane == 0) { mbits[0][tile * 4 + wave] = b0; mbits[1][tile * 4 + wave] = b1; }
        sc[0][l] = mv0 ? d0 * 0.125f : -FLT_MAX;
        sc[1][l] = mv1 ? d1 * 0.125f : -FLT_MAX;
    }
    __syncthreads();

    if (wave < QT) {
        int c = (int)__popcll(mbits[wave][lane]);
        for (int off = 32; off >= 1; off >>= 1) c += __shfl_down(c, off);
        if (lane == 0) count_s[wave] = c;
    }
    {
        float acc0 = 0.f, acc1 = 0.f;
        const int g = wave, d = lane;
        for (int wi = 0; wi < LL / 64; ++wi) {
            unsigned long long w0 = mbits[0][wi], w1 = mbits[1][wi];
            const float* vp = vmat + (size_t)(b * LL + wi * 64 + g) * DD + d;
            #pragma unroll 4
            for (int ii = 0; ii < 16; ++ii) {
                int sh = g + 4 * ii;
                float vv = vp[(size_t)(4 * ii) * DD];
                if ((w0 >> sh) & 1ULL) acc0 += vv;
                if ((w1 >> sh) & 1ULL) acc1 += vv;
            }
        }
        redv[g][0][d] = acc0; redv[g][1][d] = acc1;
    }
    __syncthreads();
    if (t < QT * DD) {
        int qt = t >> 6, dd = t & 63;
        float s2 = redv[0][qt][dd] + redv[1][qt][dd] + redv[2][qt][dd] + redv[3][qt][dd];
        int c = count_s[qt]; if (c < 1) c = 1;
        mean_s[qt][dd] = s2 / (float)c;
    }
    __syncthreads();

    for (int qt = 0; qt < QT; ++qt) {
        for (int s = 0; s < KEEP; ++s) {
            float m = -FLT_MAX; int mi = LL;
            for (int j = 0; j < NTILES; ++j) {
                int l = j * NT + t;
                float val = sc[qt][l];
                if (val > m) { m = val; mi = l; }
            }
            for (int off = 32; off >= 1; off >>= 1) {
                float ov = __shfl_down(m, off);
                int   oi = __shfl_down(mi, off);
                if (ov > m || (ov == m && oi < mi)) { m = ov; mi = oi; }
            }
            if (lane == 0) { wred[wave] = m; ired[wave] = mi; }
            __syncthreads();
            if (t == 0) {
                float bv = wred[0]; int bi = ired[0];
                for (int w2 = 1; w2 < 4; ++w2) {
                    float ov = wred[w2]; int oi = ired[w2];
                    if (ov > bv || (ov == bv && oi < bi)) { bv = ov; bi = oi; }
                }
                if (bv > -FLT_MAX) {
                    sel_idx[qt][s] = bi; sel_val[qt][s] = bv; sel_cnt[qt] = s + 1;
                    sc[qt][bi] = -FLT_MAX; brk = 0;
                } else brk = 1;
            }
            __syncthreads();
            if (brk) break;
        }
    }

    if (wave < QT) {
        int qt = wave, S = sel_cnt[qt];
        if (S > 0) {
            float mx = sel_val[qt][0];
            float e = 0.f;
            if (lane < S) e = expf(sel_val[qt][lane] - mx);
            float ssum = e;
            for (int off = 32; off >= 1; off >>= 1) ssum += __shfl_xor(ssum, off);
            if (lane < S) wgt[qt][lane] = e / ssum;
        }
    }
    __syncthreads();
    if (wave < QT) {
        int qt = wave, S = sel_cnt[qt];
        float o = mean_s[qt][lane];
        for (int j = 0; j < S; ++j)
            o += wgt[qt][j] * vmat[(size_t)(b * LL + sel_idx[qt][j]) * DD + lane];
        out[(size_t)(n0 + qt) * DD + lane] = o;
    }
}

// ============================================================================
extern "C" void kernel_launch(void* const* d_in, const int* in_sizes, int n_in,
                              void* d_out, int out_size, void* d_ws, size_t ws_size,
                              hipStream_t stream) {
    const float* q    = (const float*)d_in[0];
    const float* kmat = (const float*)d_in[1];
    const float* vmat = (const float*)d_in[2];
    const int*   mask = (const int*)d_in[3];
    float* out = (float*)d_out;

    const size_t need = (size_t)WS_TOTAL * sizeof(float);   // 14.7 MB
    if (ws_size >= need) {
        float* ws = (float*)d_ws;
        unsigned int*   ckey = (unsigned int*)(ws + WS_CKEY);
        unsigned int*   cidx = (unsigned int*)(ws + WS_CIDX);
        unsigned int*   bmw  = (unsigned int*)(ws + WS_BM);
        unsigned short* vt   = (unsigned short*)(ws + WS_VT);
        hipLaunchKernelGGL(k_scores, dim3((NROWS / RT) * NLC), dim3(256), 0, stream,
                           q, kmat, mask, ckey, cidx, (uint4*)bmw);
        hipLaunchKernelGGL(k_vt, dim3(NB * 16), dim3(256), 0, stream, vmat, vt);
        hipLaunchKernelGGL(k_mean, dim3(NROWS / 16), dim3(256), 0, stream,
                           bmw, vt, out);
        hipLaunchKernelGGL(k_merge, dim3(NROWS / 4), dim3(256), 0, stream,
                           vmat, ckey, cidx, out);
    } else {
        hipLaunchKernelGGL(ga_fused_fb, dim3(NROWS / QT), dim3(NT), 0, stream,
                           q, kmat, vmat, mask, out);
    }
}